// Round 1
// baseline (220.517 us; speedup 1.0000x reference)
//
#include <hip/hip_runtime.h>

#define VTH 0.5f
#define TAU 0.2f

// x layout: [64,128,32,32,4] fp32, steps innermost & contiguous.
// One thread = one neuron = one float4 load, 4-step LIF recurrence in
// registers, one float4 store. Purely memory-bound (32 B/thread).
__global__ __launch_bounds__(256) void lif_kernel(
    const float4* __restrict__ x, float4* __restrict__ out, int n_vec) {
    int i = blockIdx.x * blockDim.x + threadIdx.x;
    if (i >= n_vec) return;

    float4 v = x[i];

    // u=0, o=0 initially.
    float u, s0, s1, s2, s3;
    u = v.x;                               s0 = u > VTH ? 1.0f : 0.0f;
    u = TAU * u * (1.0f - s0) + v.y;       s1 = u > VTH ? 1.0f : 0.0f;
    u = TAU * u * (1.0f - s1) + v.z;       s2 = u > VTH ? 1.0f : 0.0f;
    u = TAU * u * (1.0f - s2) + v.w;       s3 = u > VTH ? 1.0f : 0.0f;

    out[i] = make_float4(s0, s1, s2, s3);
}

extern "C" void kernel_launch(void* const* d_in, const int* in_sizes, int n_in,
                              void* d_out, int out_size, void* d_ws, size_t ws_size,
                              hipStream_t stream) {
    const float4* x = (const float4*)d_in[0];
    float4* out = (float4*)d_out;
    int n_vec = in_sizes[0] / 4;  // 4 steps per neuron, steps contiguous

    int block = 256;
    int grid = (n_vec + block - 1) / block;
    lif_kernel<<<grid, block, 0, stream>>>(x, out, n_vec);
}

// Round 2
// 218.296 us; speedup vs baseline: 1.0102x; 1.0102x over previous
//
#include <hip/hip_runtime.h>

#define VTH 0.5f
#define TAU 0.2f

typedef float v4f __attribute__((ext_vector_type(4)));

// x layout: [64,128,32,32,4] fp32, steps innermost & contiguous.
// One thread = one neuron = one 16B nontemporal load, 4-step LIF recurrence
// in registers, one 16B nontemporal store. Pure streaming, zero reuse ->
// nt flag avoids L2/LLC pollution. Memory-bound: 256 MiB mandatory traffic.
__global__ __launch_bounds__(256) void lif_kernel(
    const v4f* __restrict__ x, v4f* __restrict__ out, int n_vec) {
    int i = blockIdx.x * blockDim.x + threadIdx.x;
    if (i >= n_vec) return;

    v4f v = __builtin_nontemporal_load(&x[i]);

    // u=0, o=0 initially.
    float u, s0, s1, s2, s3;
    u = v.x;                               s0 = u > VTH ? 1.0f : 0.0f;
    u = TAU * u * (1.0f - s0) + v.y;       s1 = u > VTH ? 1.0f : 0.0f;
    u = TAU * u * (1.0f - s1) + v.z;       s2 = u > VTH ? 1.0f : 0.0f;
    u = TAU * u * (1.0f - s2) + v.w;       s3 = u > VTH ? 1.0f : 0.0f;

    v4f r = {s0, s1, s2, s3};
    __builtin_nontemporal_store(r, &out[i]);
}

extern "C" void kernel_launch(void* const* d_in, const int* in_sizes, int n_in,
                              void* d_out, int out_size, void* d_ws, size_t ws_size,
                              hipStream_t stream) {
    const v4f* x = (const v4f*)d_in[0];
    v4f* out = (v4f*)d_out;
    int n_vec = in_sizes[0] / 4;  // 4 steps per neuron, steps contiguous

    int block = 256;
    int grid = (n_vec + block - 1) / block;
    lif_kernel<<<grid, block, 0, stream>>>(x, out, n_vec);
}